// Round 10
// baseline (500.294 us; speedup 1.0000x reference)
//
#include <hip/hip_runtime.h>

#define N_ATOMS 60000
#define FPD 120
#define HD 512
#define EE 3
#define BB 600
#define NNZ_C 5000000
#define NFORCE (3 * N_ATOMS)
#define TB 32
#define CBITS 12                       // 4096 cols per bucket (16KB f32 LDS)
#define NBUCK ((NFORCE + 4095) / 4096) // 44
#define NSLOT 16
#define BCAP 118000                    // fixed bucket capacity (expected 113.8K, 12 sigma)
#define SCAT_BLOCKS ((NNZ_C / 4 + 4095) / 4096)  // 306 blocks x 16384 entries
#define TPE 660                        // tiles per element (21120 atoms cap, ~9.7 sigma)
#define BL_BLOCKS ((N_ATOMS + 255) / 256)        // build_lists sub-grid (235)

typedef unsigned short ushort_t;
typedef unsigned int uint_t;
typedef unsigned long long u64_t;
typedef __attribute__((ext_vector_type(8))) __bf16 bf16x8;
typedef __attribute__((ext_vector_type(4))) float f32x4;
typedef __attribute__((ext_vector_type(4))) int i32x4;

union BF8 { f32x4 f; bf16x8 h; };

__device__ __forceinline__ ushort_t f2bf(float x) {
    uint_t u = __builtin_bit_cast(uint_t, x);
    u = (u + 0x7FFFu + ((u >> 16) & 1u)) >> 16;
    return (ushort_t)u;
}
__device__ __forceinline__ float bf2f(ushort_t s) {
    uint_t u = ((uint_t)s) << 16;
    return __builtin_bit_cast(float, u);
}
__device__ __forceinline__ float fast_tanh(float x) {
    float e2 = __expf(2.f * x);
    return fmaf(-2.f, __frcp_rn(e2 + 1.f), 1.f);
}

// ---------------- fused prep: build_lists (blocks 0..BL) + pack_all (rest) ----
#define R_W2 (EE * 16 * 32 * 512)
#define R_W1 (EE * 4 * 32 * 512)
#define R_W1T (EE * 16 * 8 * 512)
__global__ __launch_bounds__(256) void prep_all(
    const int* __restrict__ z, int* __restrict__ counts, int* __restrict__ lists,
    const float* __restrict__ W1, const float* __restrict__ W2,
    ushort_t* __restrict__ W1p, ushort_t* __restrict__ W2p,
    ushort_t* __restrict__ W2Tp, ushort_t* __restrict__ W1Tp) {
    const int t = threadIdx.x;
    if (blockIdx.x < BL_BLOCKS) {
        __shared__ int lc[3];
        __shared__ int lbase[3];
        if (t < 3) lc[t] = 0;
        __syncthreads();
        const int i = blockIdx.x * 256 + t;
        int e = 0, pos = 0;
        if (i < N_ATOMS) {
            int zi = z[i];
            e = (zi == 1) ? 0 : ((zi == 8) ? 1 : 2);
            pos = atomicAdd(&lc[e], 1);
        }
        __syncthreads();
        if (t < 3) lbase[t] = atomicAdd(&counts[t], lc[t]);
        __syncthreads();
        if (i < N_ATOMS) lists[e * N_ATOMS + lbase[e] + pos] = i;
        return;
    }
    int idx = (blockIdx.x - BL_BLOCKS) * 256 + t;
    if (idx < R_W2) {
        int p = idx;
        int j = p & 7, L = (p >> 3) & 63, ct = (p >> 9) & 31, ks = (p >> 14) & 15, e = p >> 18;
        int k = ks * 32 + ((L >> 4) << 3) + j;
        int n = (ct << 4) + (L & 15);
        W2p[p]  = f2bf(W2[((e << 9) + k) * 512 + n]);
        W2Tp[p] = f2bf(W2[((e << 9) + n) * 512 + k]);
    } else if (idx < R_W2 + R_W1) {
        int p = idx - R_W2;
        int j = p & 7, L = (p >> 3) & 63, ct = (p >> 9) & 31, ks = (p >> 14) & 3, e = p >> 16;
        int k = ks * 32 + ((L >> 4) << 3) + j;
        int n = (ct << 4) + (L & 15);
        W1p[p] = (k < FPD) ? f2bf(W1[(e * FPD + k) * 512 + n]) : (ushort_t)0;
    } else if (idx < R_W2 + R_W1 + R_W1T) {
        int p = idx - R_W2 - R_W1;
        int j = p & 7, L = (p >> 3) & 63, ct = (p >> 9) & 7, ks = (p >> 12) & 15, e = p >> 16;
        int k = ks * 32 + ((L >> 4) << 3) + j;
        int n = (ct << 4) + (L & 15);
        W1Tp[p] = (n < FPD) ? f2bf(W1[(e * FPD + n) * 512 + k]) : (ushort_t)0;
    }
}

#define STR 520
#define FSTR 136

// ---------------- fused MLP + bucket-scatter mega-kernel ----------------------
// REVERTED to the verified round-6 form: e-MAJOR block order (per-XCD L2 weight
// residency: 255us -> 205us), NO chunk skew, NO setprio, both barriers.
// Session record: every schedule-forcing change (TB=64 prefetch, chunk skew,
// setprio, direct-atomic forces) regressed; skew caused scratch traffic twice
// (rule #20 / codegen fragility: 548MB and 307MB excess WRITE_SIZE). hipcc's
// own schedule is the local optimum for this structure (cf. m131-m141).
__global__ __launch_bounds__(512, 4) void mlp_mfma(
    const float* __restrict__ fps, const int* __restrict__ image_idx,
    const float* __restrict__ b1, const float* __restrict__ b2,
    const float* __restrict__ W3, const float* __restrict__ b3,
    const ushort_t* __restrict__ W1p, const ushort_t* __restrict__ W2p,
    const ushort_t* __restrict__ W2Tp, const ushort_t* __restrict__ W1Tp,
    const int* __restrict__ counts, const int* __restrict__ lists,
    float* __restrict__ energy, ushort_t* __restrict__ g,
    const int* __restrict__ rows, const int* __restrict__ cols,
    const float* __restrict__ vals, int* __restrict__ bcnt,
    u64_t* __restrict__ bpack, int scatBlocks) {
    __shared__ ushort_t sH1[TB * STR];
    __shared__ ushort_t sD[TB * STR];
    __shared__ float sW3[512];
    __shared__ float eAcc[TB];
    __shared__ int sAtom[TB];
    __shared__ int sImg[TB];
    __shared__ int sLcnt[NBUCK];
    __shared__ int sLcur[NBUCK];

    const int t = threadIdx.x;

    if (blockIdx.x < (uint_t)scatBlocks) {
        // ---- fused bucket scatter: 16384 entries/block, 512 threads ----
        const int vk0 = blockIdx.x * 4096;
        if (t < NBUCK) sLcnt[t] = 0;
        __syncthreads();
        i32x4 cc[8];
#pragma unroll
        for (int i = 0; i < 8; i++) {
            int vk = vk0 + i * 512 + t;
            if (vk < NNZ_C / 4) {
                i32x4 c = __builtin_nontemporal_load((const i32x4*)cols + vk);
                cc[i] = c;
                atomicAdd(&sLcnt[c.x >> CBITS], 1);
                atomicAdd(&sLcnt[c.y >> CBITS], 1);
                atomicAdd(&sLcnt[c.z >> CBITS], 1);
                atomicAdd(&sLcnt[c.w >> CBITS], 1);
            } else {
                cc[i].x = -1;
            }
        }
        __syncthreads();
        if (t < NBUCK) sLcur[t] = t * BCAP + atomicAdd(&bcnt[t], sLcnt[t]);
        __syncthreads();
#pragma unroll
        for (int i = 0; i < 8; i++) {
            int vk = vk0 + i * 512 + t;
            if (cc[i].x != -1) {
                i32x4 r = __builtin_nontemporal_load((const i32x4*)rows + vk);
                f32x4 v = __builtin_nontemporal_load((const f32x4*)vals + vk);
                int rr[4] = {r.x, r.y, r.z, r.w};
                int ccv[4] = {cc[i].x, cc[i].y, cc[i].z, cc[i].w};
                float vv[4] = {v.x, v.y, v.z, v.w};
#pragma unroll
                for (int u = 0; u < 4; u++) {
                    int b = ccv[u] >> CBITS;
                    int pos = atomicAdd(&sLcur[b], 1);
                    u64_t pk = (u64_t)(uint_t)rr[u] |
                               ((u64_t)(uint_t)(ccv[u] & ((1 << CBITS) - 1)) << 23) |
                               ((u64_t)f2bf(vv[u]) << 35);
                    bpack[pos] = pk;
                }
            }
        }
        return;
    }

    // ---- MLP path: e-major mapping ----
    const int mb = blockIdx.x - scatBlocks;
    const int e = mb / TPE;
    const int tile = mb - e * TPE;
    if (e >= EE) return;
    const int cnt = counts[e];
    const int base = tile * TB;
    if (base >= cnt) return;
    const int nA = min(TB, cnt - base);
    const int* lst = lists + e * N_ATOMS + base;

    const int w = t >> 6, lane = t & 63, quad = lane >> 4, lc = lane & 15;

    if (t < TB) {
        int a = (t < nA) ? lst[t] : -1;
        sAtom[t] = a;
        sImg[t] = (a >= 0) ? image_idx[a] : 0;
        eAcc[t] = 0.f;
    }
    if (t < 512) sW3[t] = W3[e * 512 + t];
    for (int i = t; i < TB * 128; i += 512) {
        int a = i >> 7, f = i & 127;
        float v = 0.f;
        if (f < FPD && a < nA) v = __builtin_nontemporal_load(&fps[(long long)lst[a] * FPD + f]);
        sD[a * FSTR + f] = f2bf(v);
    }
    __syncthreads();

    float b1c[4], b2c[4];
#pragma unroll
    for (int c = 0; c < 4; c++) {
        int col = w * 64 + c * 16 + lc;
        b1c[c] = b1[e * 512 + col];
        b2c[c] = b2[e * 512 + col];
    }

    f32x4 acc[2][4];
    float h1f[2][4][4];  // backward mask kept in registers (32 floats)

    // ---- stage 1: h1 = tanh(fp @ W1 + b1); all 16 frags batched ----
#pragma unroll
    for (int rt = 0; rt < 2; rt++)
#pragma unroll
        for (int c = 0; c < 4; c++) acc[rt][c] = (f32x4)0.f;
    {
        const ushort_t* wbase = W1p + ((size_t)(e * 4) * 32 + w * 4) * 512 + lane * 8;
        BF8 bb[4][4];
#pragma unroll
        for (int ks = 0; ks < 4; ks++)
#pragma unroll
            for (int c = 0; c < 4; c++)
                bb[ks][c].f = *(const f32x4*)(wbase + ((size_t)ks * 32 + c) * 512);
#pragma unroll
        for (int ks = 0; ks < 4; ks++) {
            bf16x8 a0 = *(const bf16x8*)((const char*)sD + lc * (FSTR * 2) + ks * 64 + quad * 16);
            bf16x8 a1 = *(const bf16x8*)((const char*)sD + (16 + lc) * (FSTR * 2) + ks * 64 + quad * 16);
#pragma unroll
            for (int c = 0; c < 4; c++) {
                acc[0][c] = __builtin_amdgcn_mfma_f32_16x16x32_bf16(a0, bb[ks][c].h, acc[0][c], 0, 0, 0);
                acc[1][c] = __builtin_amdgcn_mfma_f32_16x16x32_bf16(a1, bb[ks][c].h, acc[1][c], 0, 0, 0);
            }
        }
    }
#pragma unroll
    for (int c = 0; c < 4; c++) {
        int col = w * 64 + c * 16 + lc;
#pragma unroll
        for (int rt = 0; rt < 2; rt++)
#pragma unroll
            for (int r = 0; r < 4; r++) {
                int row = rt * 16 + quad * 4 + r;
                float hv = fast_tanh(acc[rt][c][r] + b1c[c]);
                h1f[rt][c][r] = hv;
                sH1[row * STR + col] = f2bf(hv);
            }
    }
    __syncthreads();

    // ---- stage 2: h2 = tanh(h1 @ W2 + b2); dh2; energy (chunks of 4 ks) ----
#pragma unroll
    for (int rt = 0; rt < 2; rt++)
#pragma unroll
        for (int c = 0; c < 4; c++) acc[rt][c] = (f32x4)0.f;
    {
        const ushort_t* wbase = W2p + ((size_t)(e * 16) * 32 + w * 4) * 512 + lane * 8;
#pragma unroll
        for (int ksc = 0; ksc < 4; ksc++) {
            BF8 bb[4][4];
#pragma unroll
            for (int kk = 0; kk < 4; kk++)
#pragma unroll
                for (int c = 0; c < 4; c++)
                    bb[kk][c].f = *(const f32x4*)(wbase + (size_t)(ksc * 4 + kk) * 32 * 512 + (size_t)c * 512);
#pragma unroll
            for (int kk = 0; kk < 4; kk++) {
                int ks = ksc * 4 + kk;
                bf16x8 a0 = *(const bf16x8*)((const char*)sH1 + lc * (STR * 2) + ks * 64 + quad * 16);
                bf16x8 a1 = *(const bf16x8*)((const char*)sH1 + (16 + lc) * (STR * 2) + ks * 64 + quad * 16);
#pragma unroll
                for (int c = 0; c < 4; c++) {
                    acc[0][c] = __builtin_amdgcn_mfma_f32_16x16x32_bf16(a0, bb[kk][c].h, acc[0][c], 0, 0, 0);
                    acc[1][c] = __builtin_amdgcn_mfma_f32_16x16x32_bf16(a1, bb[kk][c].h, acc[1][c], 0, 0, 0);
                }
            }
        }
    }
    {
        float ep[2][4];
#pragma unroll
        for (int rt = 0; rt < 2; rt++)
#pragma unroll
            for (int r = 0; r < 4; r++) ep[rt][r] = 0.f;
#pragma unroll
        for (int c = 0; c < 4; c++) {
            int col = w * 64 + c * 16 + lc;
            float w3c = sW3[col];
#pragma unroll
            for (int rt = 0; rt < 2; rt++)
#pragma unroll
                for (int r = 0; r < 4; r++) {
                    int row = rt * 16 + quad * 4 + r;
                    float h2 = fast_tanh(acc[rt][c][r] + b2c[c]);
                    ep[rt][r] += h2 * w3c;
                    sD[row * STR + col] = f2bf(w3c * (1.f - h2 * h2));
                }
        }
#pragma unroll
        for (int rt = 0; rt < 2; rt++)
#pragma unroll
            for (int r = 0; r < 4; r++) {
                float p = ep[rt][r];
                p += __shfl_xor(p, 1);
                p += __shfl_xor(p, 2);
                p += __shfl_xor(p, 4);
                p += __shfl_xor(p, 8);
                if (lc == 0) atomicAdd(&eAcc[rt * 16 + quad * 4 + r], p);
            }
    }
    __syncthreads();

    if (t < nA) atomicAdd(&energy[sImg[t]], eAcc[t] + b3[e]);

    // ---- stage 5: dh1 = (dh2 @ W2^T) * (1-h1^2) (chunks of 4 ks) ----
#pragma unroll
    for (int rt = 0; rt < 2; rt++)
#pragma unroll
        for (int c = 0; c < 4; c++) acc[rt][c] = (f32x4)0.f;
    {
        const ushort_t* wbase = W2Tp + ((size_t)(e * 16) * 32 + w * 4) * 512 + lane * 8;
#pragma unroll
        for (int ksc = 0; ksc < 4; ksc++) {
            BF8 bb[4][4];
#pragma unroll
            for (int kk = 0; kk < 4; kk++)
#pragma unroll
                for (int c = 0; c < 4; c++)
                    bb[kk][c].f = *(const f32x4*)(wbase + (size_t)(ksc * 4 + kk) * 32 * 512 + (size_t)c * 512);
#pragma unroll
            for (int kk = 0; kk < 4; kk++) {
                int ks = ksc * 4 + kk;
                bf16x8 a0 = *(const bf16x8*)((const char*)sD + lc * (STR * 2) + ks * 64 + quad * 16);
                bf16x8 a1 = *(const bf16x8*)((const char*)sD + (16 + lc) * (STR * 2) + ks * 64 + quad * 16);
#pragma unroll
                for (int c = 0; c < 4; c++) {
                    acc[0][c] = __builtin_amdgcn_mfma_f32_16x16x32_bf16(a0, bb[kk][c].h, acc[0][c], 0, 0, 0);
                    acc[1][c] = __builtin_amdgcn_mfma_f32_16x16x32_bf16(a1, bb[kk][c].h, acc[1][c], 0, 0, 0);
                }
            }
        }
    }
    // mask from registers: same (row,col) elements this thread produced in stage 1
#pragma unroll
    for (int c = 0; c < 4; c++)
#pragma unroll
        for (int rt = 0; rt < 2; rt++)
#pragma unroll
            for (int r = 0; r < 4; r++) {
                float hv = h1f[rt][c][r];
                acc[rt][c][r] *= (1.f - hv * hv);
            }
    __syncthreads();
#pragma unroll
    for (int c = 0; c < 4; c++) {
        int col = w * 64 + c * 16 + lc;
#pragma unroll
        for (int rt = 0; rt < 2; rt++)
#pragma unroll
            for (int r = 0; r < 4; r++) {
                int row = rt * 16 + quad * 4 + r;
                sH1[row * STR + col] = f2bf(acc[rt][c][r]);
            }
    }
    __syncthreads();

    // ---- stage 7: g = dh1 @ W1^T (2 chunks of 8 frags) ----
    f32x4 acc7[2];
#pragma unroll
    for (int rt = 0; rt < 2; rt++) acc7[rt] = (f32x4)0.f;
    {
        const ushort_t* wbase = W1Tp + ((size_t)(e * 16) * 8 + w) * 512 + lane * 8;
#pragma unroll
        for (int ksc = 0; ksc < 2; ksc++) {
            BF8 bb[8];
#pragma unroll
            for (int kk = 0; kk < 8; kk++)
                bb[kk].f = *(const f32x4*)(wbase + (size_t)(ksc * 8 + kk) * 8 * 512);
#pragma unroll
            for (int kk = 0; kk < 8; kk++) {
                int ks = ksc * 8 + kk;
                bf16x8 a0 = *(const bf16x8*)((const char*)sH1 + lc * (STR * 2) + ks * 64 + quad * 16);
                bf16x8 a1 = *(const bf16x8*)((const char*)sH1 + (16 + lc) * (STR * 2) + ks * 64 + quad * 16);
                acc7[0] = __builtin_amdgcn_mfma_f32_16x16x32_bf16(a0, bb[kk].h, acc7[0], 0, 0, 0);
                acc7[1] = __builtin_amdgcn_mfma_f32_16x16x32_bf16(a1, bb[kk].h, acc7[1], 0, 0, 0);
            }
        }
    }
    {
        int col = w * 16 + lc;
#pragma unroll
        for (int rt = 0; rt < 2; rt++)
#pragma unroll
            for (int r = 0; r < 4; r++) {
                int row = rt * 16 + quad * 4 + r;
                if (col < FPD && row < nA)
                    g[(long long)sAtom[row] * FPD + col] = f2bf(acc7[rt][r]);
            }
    }
}

// scatter_lds_cap with fused final reduction: the LAST slot-block per bucket
// (device-scope ticket) sums the 16 forcesP slot segments (L2-warm, just
// written) into forces. Removes the reduce_forces launch + its HBM re-read.
// Ordering: producers store (plain, coherent), __threadfence (release),
// atomicAdd ticket (device scope); consumer observes ticket==15, __threadfence
// (acquire), then reads all slots.
__global__ __launch_bounds__(256) void scatter_lds_cap(
    const u64_t* __restrict__ bpack, const int* __restrict__ bcnt,
    const ushort_t* __restrict__ g, float* __restrict__ forcesP,
    int* __restrict__ done, float* __restrict__ forces) {
    __shared__ float facc[1 << CBITS];
    __shared__ int ticket;
    const int b = blockIdx.x >> 4;
    const int s = blockIdx.x & (NSLOT - 1);
    const int t = threadIdx.x;
    for (int i = t; i < (1 << CBITS); i += 256) facc[i] = 0.f;
    __syncthreads();
    const int base = b * BCAP;
    const int end = base + bcnt[b];
    for (int i = base + s * 256 + t; i < end; i += NSLOT * 256) {
        u64_t pk = bpack[i];
        int r = (int)(pk & 0x7FFFFFu);
        int cin = (int)((pk >> 23) & 0xFFFu);
        float v = bf2f((ushort_t)(pk >> 35));
        atomicAdd(&facc[cin], -v * bf2f(g[r]));
    }
    __syncthreads();
    const int colbase = b << CBITS;
    {
        float* fp = forcesP + (size_t)s * NFORCE;
        for (int i = t; i < (1 << CBITS); i += 256) {
            int col = colbase + i;
            if (col < NFORCE) fp[col] = facc[i];
        }
    }
    __threadfence();  // release: slot segment visible device-wide
    if (t == 0) ticket = atomicAdd(&done[b], 1);
    __syncthreads();
    if (ticket == NSLOT - 1) {
        __threadfence();  // acquire: see all other slots' stores
        for (int i = t; i < (1 << CBITS); i += 256) {
            int col = colbase + i;
            if (col < NFORCE) {
                float ssum = 0.f;
#pragma unroll
                for (int x = 0; x < NSLOT; x++) ssum += forcesP[(size_t)x * NFORCE + col];
                forces[col] = ssum;
            }
        }
    }
}

// ---------------- fallback path kernels (round-0 exact) -----------------------
__global__ __launch_bounds__(256) void bucket_hist(const int* __restrict__ cols,
                                                   int* __restrict__ bcnt) {
    __shared__ int h[NBUCK];
    const int t = threadIdx.x;
    if (t < NBUCK) h[t] = 0;
    __syncthreads();
    const int nv = NNZ_C / 4;
    for (int vk = blockIdx.x * 256 + t; vk < nv; vk += gridDim.x * 256) {
        i32x4 c = __builtin_nontemporal_load((const i32x4*)cols + vk);
        atomicAdd(&h[c.x >> CBITS], 1);
        atomicAdd(&h[c.y >> CBITS], 1);
        atomicAdd(&h[c.z >> CBITS], 1);
        atomicAdd(&h[c.w >> CBITS], 1);
    }
    __syncthreads();
    if (t < NBUCK) atomicAdd(&bcnt[t], h[t]);
}

__global__ void bucket_scan(const int* __restrict__ bcnt, int* __restrict__ bbase,
                            int* __restrict__ bcur) {
    if (threadIdx.x == 0 && blockIdx.x == 0) {
        int s = 0;
        for (int i = 0; i < NBUCK; i++) { bbase[i] = s; bcur[i] = s; s += bcnt[i]; }
    }
}

__global__ __launch_bounds__(256) void bucket_scatter(
    const int* __restrict__ rows, const int* __restrict__ cols,
    const float* __restrict__ vals, int* __restrict__ bcur,
    u64_t* __restrict__ bpack) {
    __shared__ int lcnt[NBUCK];
    __shared__ int lcur[NBUCK];
    const int t = threadIdx.x;
    if (t < NBUCK) lcnt[t] = 0;
    __syncthreads();
    const int vk0 = blockIdx.x * 2048;
    i32x4 ccache[8];
    int nb[8][4];
#pragma unroll
    for (int i = 0; i < 8; i++) {
        int vk = vk0 + i * 256 + t;
        if (vk * 4 < NNZ_C) {
            i32x4 c = __builtin_nontemporal_load((const i32x4*)cols + vk);
            ccache[i] = c;
            nb[i][0] = c.x >> CBITS; nb[i][1] = c.y >> CBITS;
            nb[i][2] = c.z >> CBITS; nb[i][3] = c.w >> CBITS;
            atomicAdd(&lcnt[nb[i][0]], 1);
            atomicAdd(&lcnt[nb[i][1]], 1);
            atomicAdd(&lcnt[nb[i][2]], 1);
            atomicAdd(&lcnt[nb[i][3]], 1);
        } else {
            nb[i][0] = -1;
        }
    }
    __syncthreads();
    if (t < NBUCK) lcur[t] = atomicAdd(&bcur[t], lcnt[t]);
    __syncthreads();
#pragma unroll
    for (int i = 0; i < 8; i++) {
        int vk = vk0 + i * 256 + t;
        if (vk * 4 < NNZ_C) {
            i32x4 r = __builtin_nontemporal_load((const i32x4*)rows + vk);
            f32x4 v = __builtin_nontemporal_load((const f32x4*)vals + vk);
            int rr[4] = {r.x, r.y, r.z, r.w};
            int cc[4] = {ccache[i].x, ccache[i].y, ccache[i].z, ccache[i].w};
            float vv[4] = {v.x, v.y, v.z, v.w};
#pragma unroll
            for (int u = 0; u < 4; u++) {
                int pos = atomicAdd(&lcur[nb[i][u]], 1);
                u64_t pk = (u64_t)(uint_t)rr[u] |
                           ((u64_t)(uint_t)(cc[u] & ((1 << CBITS) - 1)) << 23) |
                           ((u64_t)f2bf(vv[u]) << 35);
                bpack[pos] = pk;
            }
        }
    }
}

__global__ __launch_bounds__(256) void scatter_lds(
    const u64_t* __restrict__ bpack, const int* __restrict__ bbase,
    const int* __restrict__ bcnt, const ushort_t* __restrict__ g,
    float* __restrict__ forcesP) {
    __shared__ float facc[1 << CBITS];
    const int b = blockIdx.x >> 4;
    const int s = blockIdx.x & (NSLOT - 1);
    const int t = threadIdx.x;
    for (int i = t; i < (1 << CBITS); i += 256) facc[i] = 0.f;
    __syncthreads();
    const int base = bbase[b];
    const int end = base + bcnt[b];
    for (int i = base + s * 256 + t; i < end; i += NSLOT * 256) {
        u64_t pk = bpack[i];
        int r = (int)(pk & 0x7FFFFFu);
        int cin = (int)((pk >> 23) & 0xFFFu);
        float v = bf2f((ushort_t)(pk >> 35));
        atomicAdd(&facc[cin], -v * bf2f(g[r]));
    }
    __syncthreads();
    const int colbase = b << CBITS;
    float* fp = forcesP + (size_t)s * NFORCE;
    for (int i = t; i < (1 << CBITS); i += 256) {
        int col = colbase + i;
        if (col < NFORCE) __builtin_nontemporal_store(facc[i], &fp[col]);
    }
}

__global__ void reduce_forces(const float* __restrict__ forcesP, float* __restrict__ forces) {
    int i = blockIdx.x * blockDim.x + threadIdx.x;
    if (i >= NFORCE) return;
    float s = 0.f;
#pragma unroll
    for (int x = 0; x < NSLOT; x++) s += forcesP[(size_t)x * NFORCE + i];
    forces[i] = s;
}

__global__ __launch_bounds__(256) void scatter_forces(
    const int* __restrict__ rows, const int* __restrict__ cols,
    const float* __restrict__ vals, const ushort_t* __restrict__ g,
    float* __restrict__ forcesP) {
    int k = blockIdx.x * 256 + threadIdx.x;
    if (k >= NNZ_C / 4) return;
    int slot = blockIdx.x & (NSLOT - 1);
    i32x4 r = __builtin_nontemporal_load((const i32x4*)rows + k);
    i32x4 c = __builtin_nontemporal_load((const i32x4*)cols + k);
    f32x4 v = __builtin_nontemporal_load((const f32x4*)vals + k);
    float* fp = forcesP + (size_t)slot * NFORCE;
    atomicAdd(&fp[c.x], -v.x * bf2f(g[r.x]));
    atomicAdd(&fp[c.y], -v.y * bf2f(g[r.y]));
    atomicAdd(&fp[c.z], -v.z * bf2f(g[r.z]));
    atomicAdd(&fp[c.w], -v.w * bf2f(g[r.w]));
}

extern "C" void kernel_launch(void* const* d_in, const int* in_sizes, int n_in,
                              void* d_out, int out_size, void* d_ws, size_t ws_size,
                              hipStream_t stream) {
    const float* fps = (const float*)d_in[0];
    const int* z = (const int*)d_in[1];
    const int* img = (const int*)d_in[2];
    const float* W1 = (const float*)d_in[3];
    const float* b1 = (const float*)d_in[4];
    const float* W2 = (const float*)d_in[5];
    const float* b2 = (const float*)d_in[6];
    const float* W3 = (const float*)d_in[7];
    const float* b3 = (const float*)d_in[8];
    const int* rows = (const int*)d_in[9];
    const int* cols = (const int*)d_in[10];
    const float* vals = (const float*)d_in[11];

    float* out = (float*)d_out;
    float* energy = out;
    float* forces = out + BB;

    char* ws = (char*)d_ws;
    int* counts = (int*)ws;                           // 256 B
    int* lists = (int*)(ws + 256);                    // 720000 B
    ushort_t* W1p = (ushort_t*)(ws + 720384);         // 393216 B
    ushort_t* W2p = (ushort_t*)(ws + 1113600);        // 1572864 B
    ushort_t* W2Tp = (ushort_t*)(ws + 2686464);       // 1572864 B
    ushort_t* W1Tp = (ushort_t*)(ws + 4259328);       // 393216 B
    ushort_t* g = (ushort_t*)(ws + 4652544);          // 14400000 B
    float* forcesP = (float*)(ws + 19052544);         // 16*720000 = 11520000 B
    int* bmeta = (int*)(ws + 30572544);               // bcnt[64],bbase[64],bcur[64],done[64]
    int* bcnt = bmeta, *bbase = bmeta + 64, *bcur = bmeta + 128, *done = bmeta + 192;
    u64_t* bpack = (u64_t*)(ws + 30573568);
    const size_t WS_FAST = 30573568ull + (size_t)NBUCK * BCAP * 8;  // 72,109,568
    const size_t WS_NEED = 70573568;                                // packed layout
    (void)in_sizes; (void)n_in; (void)out_size;

    (void)hipMemsetAsync(energy, 0, BB * sizeof(float), stream);
    (void)hipMemsetAsync(counts, 0, 256, stream);

    const int PACK_BLOCKS = (R_W2 + R_W1 + R_W1T + 255) / 256;
    prep_all<<<BL_BLOCKS + PACK_BLOCKS, 256, 0, stream>>>(
        z, counts, lists, W1, W2, W1p, W2p, W2Tp, W1Tp);

    int tiles = (N_ATOMS + TB - 1) / TB;

    if (ws_size >= WS_FAST) {
        // fast path: fused scatter+MLP (e-major); scatter_lds_cap w/ fused reduce
        (void)hipMemsetAsync(bmeta, 0, 1024, stream);  // includes done[]
        mlp_mfma<<<SCAT_BLOCKS + EE * TPE, 512, 0, stream>>>(
            fps, img, b1, b2, W3, b3, W1p, W2p, W2Tp, W1Tp,
            counts, lists, energy, g,
            rows, cols, vals, bcnt, bpack, SCAT_BLOCKS);
        scatter_lds_cap<<<NBUCK * NSLOT, 256, 0, stream>>>(bpack, bcnt, g,
                                                           forcesP, done, forces);
    } else if (ws_size >= WS_NEED) {
        // round-0 path: serial hist/scan/scatter with packed buckets
        (void)hipMemsetAsync(bmeta, 0, 768, stream);
        mlp_mfma<<<EE * tiles, 512, 0, stream>>>(
            fps, img, b1, b2, W3, b3, W1p, W2p, W2Tp, W1Tp,
            counts, lists, energy, g,
            rows, cols, vals, bcnt, bpack, 0);
        bucket_hist<<<256, 256, 0, stream>>>(cols, bcnt);
        bucket_scan<<<1, 64, 0, stream>>>(bcnt, bbase, bcur);
        bucket_scatter<<<(NNZ_C + 8191) / 8192, 256, 0, stream>>>(
            rows, cols, vals, bcur, bpack);
        scatter_lds<<<NBUCK * NSLOT, 256, 0, stream>>>(bpack, bbase, bcnt, g, forcesP);
        reduce_forces<<<(NFORCE + 255) / 256, 256, 0, stream>>>(forcesP, forces);
    } else {
        (void)hipMemsetAsync(forcesP, 0, (size_t)NSLOT * NFORCE * sizeof(float), stream);
        mlp_mfma<<<EE * tiles, 512, 0, stream>>>(
            fps, img, b1, b2, W3, b3, W1p, W2p, W2Tp, W1Tp,
            counts, lists, energy, g,
            rows, cols, vals, bcnt, (u64_t*)forcesP /*unused*/, 0);
        scatter_forces<<<(NNZ_C / 4 + 255) / 256, 256, 0, stream>>>(rows, cols, vals, g, forcesP);
        reduce_forces<<<(NFORCE + 255) / 256, 256, 0, stream>>>(forcesP, forces);
    }
}

// Round 11
// 389.426 us; speedup vs baseline: 1.2847x; 1.2847x over previous
//
#include <hip/hip_runtime.h>

#define N_ATOMS 60000
#define FPD 120
#define HD 512
#define EE 3
#define BB 600
#define NNZ_C 5000000
#define NFORCE (3 * N_ATOMS)
#define TB 32
#define CBITS 12                       // 4096 cols per bucket (16KB f32 LDS)
#define NBUCK ((NFORCE + 4095) / 4096) // 44
#define NSLOT 16
#define BCAP 118000                    // fixed bucket capacity (expected 113.8K, 12 sigma)
#define SCAT_BLOCKS ((NNZ_C / 4 + 4095) / 4096)  // 306 blocks x 16384 entries
#define TPE 660                        // tiles per element (21120 atoms cap, ~9.7 sigma)

typedef unsigned short ushort_t;
typedef unsigned int uint_t;
typedef unsigned long long u64_t;
typedef __attribute__((ext_vector_type(8))) __bf16 bf16x8;
typedef __attribute__((ext_vector_type(4))) float f32x4;
typedef __attribute__((ext_vector_type(4))) int i32x4;

union BF8 { f32x4 f; bf16x8 h; };

__device__ __forceinline__ ushort_t f2bf(float x) {
    uint_t u = __builtin_bit_cast(uint_t, x);
    u = (u + 0x7FFFu + ((u >> 16) & 1u)) >> 16;
    return (ushort_t)u;
}
__device__ __forceinline__ float bf2f(ushort_t s) {
    uint_t u = ((uint_t)s) << 16;
    return __builtin_bit_cast(float, u);
}
__device__ __forceinline__ float fast_tanh(float x) {
    float e2 = __expf(2.f * x);
    return fmaf(-2.f, __frcp_rn(e2 + 1.f), 1.f);
}

// ---------------- build per-element atom lists (block-aggregated atomics) -----
__global__ __launch_bounds__(256) void build_lists(const int* __restrict__ z,
                                                   int* __restrict__ counts,
                                                   int* __restrict__ lists) {
    __shared__ int lc[3];
    __shared__ int lbase[3];
    const int t = threadIdx.x;
    if (t < 3) lc[t] = 0;
    __syncthreads();
    const int i = blockIdx.x * 256 + t;
    int e = 0, pos = 0;
    if (i < N_ATOMS) {
        int zi = z[i];
        e = (zi == 1) ? 0 : ((zi == 8) ? 1 : 2);
        pos = atomicAdd(&lc[e], 1);
    }
    __syncthreads();
    if (t < 3) lbase[t] = atomicAdd(&counts[t], lc[t]);
    __syncthreads();
    if (i < N_ATOMS) lists[e * N_ATOMS + lbase[e] + pos] = i;
}

// ---------------- pack all weights (fused) into MFMA B-fragment order --------
// Lane L of B-frag holds B[k = ks*32 + (L>>4)*8 + j][n = ct*16 + (L&15)], j=0..7.
#define R_W2 (EE * 16 * 32 * 512)
#define R_W1 (EE * 4 * 32 * 512)
#define R_W1T (EE * 16 * 8 * 512)
__global__ __launch_bounds__(256) void pack_all(
    const float* __restrict__ W1, const float* __restrict__ W2,
    ushort_t* __restrict__ W1p, ushort_t* __restrict__ W2p,
    ushort_t* __restrict__ W2Tp, ushort_t* __restrict__ W1Tp) {
    int idx = blockIdx.x * 256 + threadIdx.x;
    if (idx < R_W2) {
        int p = idx;
        int j = p & 7, L = (p >> 3) & 63, ct = (p >> 9) & 31, ks = (p >> 14) & 15, e = p >> 18;
        int k = ks * 32 + ((L >> 4) << 3) + j;
        int n = (ct << 4) + (L & 15);
        W2p[p]  = f2bf(W2[((e << 9) + k) * 512 + n]);
        W2Tp[p] = f2bf(W2[((e << 9) + n) * 512 + k]);
    } else if (idx < R_W2 + R_W1) {
        int p = idx - R_W2;
        int j = p & 7, L = (p >> 3) & 63, ct = (p >> 9) & 31, ks = (p >> 14) & 3, e = p >> 16;
        int k = ks * 32 + ((L >> 4) << 3) + j;
        int n = (ct << 4) + (L & 15);
        W1p[p] = (k < FPD) ? f2bf(W1[(e * FPD + k) * 512 + n]) : (ushort_t)0;
    } else if (idx < R_W2 + R_W1 + R_W1T) {
        int p = idx - R_W2 - R_W1;
        int j = p & 7, L = (p >> 3) & 63, ct = (p >> 9) & 7, ks = (p >> 12) & 15, e = p >> 16;
        int k = ks * 32 + ((L >> 4) << 3) + j;
        int n = (ct << 4) + (L & 15);
        W1Tp[p] = (n < FPD) ? f2bf(W1[(e * FPD + n) * 512 + k]) : (ushort_t)0;
    }
}

#define STR 520
#define FSTR 136

// ---------------- fused MLP + bucket-scatter mega-kernel ----------------------
// BEST-MEASURED CONFIG (round 7: 394.6us total, fused 205us). e-MAJOR block
// order for per-XCD L2 weight residency (one element's 1.3MB weight set per
// XCD instead of 3.9MB thrashing the 4MiB L2: 255 -> 205us). No chunk skew,
// no setprio, both barriers: every schedule-forcing variant regressed
// (TB=64 prefetch +26us; skew = scratch traffic 548/307MB; setprio null on
// lockstep waves; ticket-reduce +105us). hipcc's schedule is the local
// optimum for this structure (cf. guide m131-m141).
__global__ __launch_bounds__(512, 4) void mlp_mfma(
    const float* __restrict__ fps, const int* __restrict__ image_idx,
    const float* __restrict__ b1, const float* __restrict__ b2,
    const float* __restrict__ W3, const float* __restrict__ b3,
    const ushort_t* __restrict__ W1p, const ushort_t* __restrict__ W2p,
    const ushort_t* __restrict__ W2Tp, const ushort_t* __restrict__ W1Tp,
    const int* __restrict__ counts, const int* __restrict__ lists,
    float* __restrict__ energy, ushort_t* __restrict__ g,
    const int* __restrict__ rows, const int* __restrict__ cols,
    const float* __restrict__ vals, int* __restrict__ bcnt,
    u64_t* __restrict__ bpack, int scatBlocks) {
    __shared__ ushort_t sH1[TB * STR];
    __shared__ ushort_t sD[TB * STR];
    __shared__ float sW3[512];
    __shared__ float eAcc[TB];
    __shared__ int sAtom[TB];
    __shared__ int sImg[TB];
    __shared__ int sLcnt[NBUCK];
    __shared__ int sLcur[NBUCK];

    const int t = threadIdx.x;

    if (blockIdx.x < (uint_t)scatBlocks) {
        // ---- fused bucket scatter: 16384 entries/block, 512 threads ----
        const int vk0 = blockIdx.x * 4096;
        if (t < NBUCK) sLcnt[t] = 0;
        __syncthreads();
        i32x4 cc[8];
#pragma unroll
        for (int i = 0; i < 8; i++) {
            int vk = vk0 + i * 512 + t;
            if (vk < NNZ_C / 4) {
                i32x4 c = __builtin_nontemporal_load((const i32x4*)cols + vk);
                cc[i] = c;
                atomicAdd(&sLcnt[c.x >> CBITS], 1);
                atomicAdd(&sLcnt[c.y >> CBITS], 1);
                atomicAdd(&sLcnt[c.z >> CBITS], 1);
                atomicAdd(&sLcnt[c.w >> CBITS], 1);
            } else {
                cc[i].x = -1;
            }
        }
        __syncthreads();
        if (t < NBUCK) sLcur[t] = t * BCAP + atomicAdd(&bcnt[t], sLcnt[t]);
        __syncthreads();
#pragma unroll
        for (int i = 0; i < 8; i++) {
            int vk = vk0 + i * 512 + t;
            if (cc[i].x != -1) {
                i32x4 r = __builtin_nontemporal_load((const i32x4*)rows + vk);
                f32x4 v = __builtin_nontemporal_load((const f32x4*)vals + vk);
                int rr[4] = {r.x, r.y, r.z, r.w};
                int ccv[4] = {cc[i].x, cc[i].y, cc[i].z, cc[i].w};
                float vv[4] = {v.x, v.y, v.z, v.w};
#pragma unroll
                for (int u = 0; u < 4; u++) {
                    int b = ccv[u] >> CBITS;
                    int pos = atomicAdd(&sLcur[b], 1);
                    u64_t pk = (u64_t)(uint_t)rr[u] |
                               ((u64_t)(uint_t)(ccv[u] & ((1 << CBITS) - 1)) << 23) |
                               ((u64_t)f2bf(vv[u]) << 35);
                    bpack[pos] = pk;
                }
            }
        }
        return;
    }

    // ---- MLP path: e-major mapping ----
    const int mb = blockIdx.x - scatBlocks;
    const int e = mb / TPE;
    const int tile = mb - e * TPE;
    if (e >= EE) return;
    const int cnt = counts[e];
    const int base = tile * TB;
    if (base >= cnt) return;
    const int nA = min(TB, cnt - base);
    const int* lst = lists + e * N_ATOMS + base;

    const int w = t >> 6, lane = t & 63, quad = lane >> 4, lc = lane & 15;

    if (t < TB) {
        int a = (t < nA) ? lst[t] : -1;
        sAtom[t] = a;
        sImg[t] = (a >= 0) ? image_idx[a] : 0;
        eAcc[t] = 0.f;
    }
    if (t < 512) sW3[t] = W3[e * 512 + t];
    for (int i = t; i < TB * 128; i += 512) {
        int a = i >> 7, f = i & 127;
        float v = 0.f;
        if (f < FPD && a < nA) v = __builtin_nontemporal_load(&fps[(long long)lst[a] * FPD + f]);
        sD[a * FSTR + f] = f2bf(v);
    }
    __syncthreads();

    float b1c[4], b2c[4];
#pragma unroll
    for (int c = 0; c < 4; c++) {
        int col = w * 64 + c * 16 + lc;
        b1c[c] = b1[e * 512 + col];
        b2c[c] = b2[e * 512 + col];
    }

    f32x4 acc[2][4];
    float h1f[2][4][4];  // backward mask kept in registers (32 floats)

    // ---- stage 1: h1 = tanh(fp @ W1 + b1); all 16 frags batched ----
#pragma unroll
    for (int rt = 0; rt < 2; rt++)
#pragma unroll
        for (int c = 0; c < 4; c++) acc[rt][c] = (f32x4)0.f;
    {
        const ushort_t* wbase = W1p + ((size_t)(e * 4) * 32 + w * 4) * 512 + lane * 8;
        BF8 bb[4][4];
#pragma unroll
        for (int ks = 0; ks < 4; ks++)
#pragma unroll
            for (int c = 0; c < 4; c++)
                bb[ks][c].f = *(const f32x4*)(wbase + ((size_t)ks * 32 + c) * 512);
#pragma unroll
        for (int ks = 0; ks < 4; ks++) {
            bf16x8 a0 = *(const bf16x8*)((const char*)sD + lc * (FSTR * 2) + ks * 64 + quad * 16);
            bf16x8 a1 = *(const bf16x8*)((const char*)sD + (16 + lc) * (FSTR * 2) + ks * 64 + quad * 16);
#pragma unroll
            for (int c = 0; c < 4; c++) {
                acc[0][c] = __builtin_amdgcn_mfma_f32_16x16x32_bf16(a0, bb[ks][c].h, acc[0][c], 0, 0, 0);
                acc[1][c] = __builtin_amdgcn_mfma_f32_16x16x32_bf16(a1, bb[ks][c].h, acc[1][c], 0, 0, 0);
            }
        }
    }
#pragma unroll
    for (int c = 0; c < 4; c++) {
        int col = w * 64 + c * 16 + lc;
#pragma unroll
        for (int rt = 0; rt < 2; rt++)
#pragma unroll
            for (int r = 0; r < 4; r++) {
                int row = rt * 16 + quad * 4 + r;
                float hv = fast_tanh(acc[rt][c][r] + b1c[c]);
                h1f[rt][c][r] = hv;
                sH1[row * STR + col] = f2bf(hv);
            }
    }
    __syncthreads();

    // ---- stage 2: h2 = tanh(h1 @ W2 + b2); dh2; energy (chunks of 4 ks) ----
#pragma unroll
    for (int rt = 0; rt < 2; rt++)
#pragma unroll
        for (int c = 0; c < 4; c++) acc[rt][c] = (f32x4)0.f;
    {
        const ushort_t* wbase = W2p + ((size_t)(e * 16) * 32 + w * 4) * 512 + lane * 8;
#pragma unroll
        for (int ksc = 0; ksc < 4; ksc++) {
            BF8 bb[4][4];
#pragma unroll
            for (int kk = 0; kk < 4; kk++)
#pragma unroll
                for (int c = 0; c < 4; c++)
                    bb[kk][c].f = *(const f32x4*)(wbase + (size_t)(ksc * 4 + kk) * 32 * 512 + (size_t)c * 512);
#pragma unroll
            for (int kk = 0; kk < 4; kk++) {
                int ks = ksc * 4 + kk;
                bf16x8 a0 = *(const bf16x8*)((const char*)sH1 + lc * (STR * 2) + ks * 64 + quad * 16);
                bf16x8 a1 = *(const bf16x8*)((const char*)sH1 + (16 + lc) * (STR * 2) + ks * 64 + quad * 16);
#pragma unroll
                for (int c = 0; c < 4; c++) {
                    acc[0][c] = __builtin_amdgcn_mfma_f32_16x16x32_bf16(a0, bb[kk][c].h, acc[0][c], 0, 0, 0);
                    acc[1][c] = __builtin_amdgcn_mfma_f32_16x16x32_bf16(a1, bb[kk][c].h, acc[1][c], 0, 0, 0);
                }
            }
        }
    }
    {
        float ep[2][4];
#pragma unroll
        for (int rt = 0; rt < 2; rt++)
#pragma unroll
            for (int r = 0; r < 4; r++) ep[rt][r] = 0.f;
#pragma unroll
        for (int c = 0; c < 4; c++) {
            int col = w * 64 + c * 16 + lc;
            float w3c = sW3[col];
#pragma unroll
            for (int rt = 0; rt < 2; rt++)
#pragma unroll
                for (int r = 0; r < 4; r++) {
                    int row = rt * 16 + quad * 4 + r;
                    float h2 = fast_tanh(acc[rt][c][r] + b2c[c]);
                    ep[rt][r] += h2 * w3c;
                    sD[row * STR + col] = f2bf(w3c * (1.f - h2 * h2));
                }
        }
#pragma unroll
        for (int rt = 0; rt < 2; rt++)
#pragma unroll
            for (int r = 0; r < 4; r++) {
                float p = ep[rt][r];
                p += __shfl_xor(p, 1);
                p += __shfl_xor(p, 2);
                p += __shfl_xor(p, 4);
                p += __shfl_xor(p, 8);
                if (lc == 0) atomicAdd(&eAcc[rt * 16 + quad * 4 + r], p);
            }
    }
    __syncthreads();

    if (t < nA) atomicAdd(&energy[sImg[t]], eAcc[t] + b3[e]);

    // ---- stage 5: dh1 = (dh2 @ W2^T) * (1-h1^2) (chunks of 4 ks) ----
#pragma unroll
    for (int rt = 0; rt < 2; rt++)
#pragma unroll
        for (int c = 0; c < 4; c++) acc[rt][c] = (f32x4)0.f;
    {
        const ushort_t* wbase = W2Tp + ((size_t)(e * 16) * 32 + w * 4) * 512 + lane * 8;
#pragma unroll
        for (int ksc = 0; ksc < 4; ksc++) {
            BF8 bb[4][4];
#pragma unroll
            for (int kk = 0; kk < 4; kk++)
#pragma unroll
                for (int c = 0; c < 4; c++)
                    bb[kk][c].f = *(const f32x4*)(wbase + (size_t)(ksc * 4 + kk) * 32 * 512 + (size_t)c * 512);
#pragma unroll
            for (int kk = 0; kk < 4; kk++) {
                int ks = ksc * 4 + kk;
                bf16x8 a0 = *(const bf16x8*)((const char*)sD + lc * (STR * 2) + ks * 64 + quad * 16);
                bf16x8 a1 = *(const bf16x8*)((const char*)sD + (16 + lc) * (STR * 2) + ks * 64 + quad * 16);
#pragma unroll
                for (int c = 0; c < 4; c++) {
                    acc[0][c] = __builtin_amdgcn_mfma_f32_16x16x32_bf16(a0, bb[kk][c].h, acc[0][c], 0, 0, 0);
                    acc[1][c] = __builtin_amdgcn_mfma_f32_16x16x32_bf16(a1, bb[kk][c].h, acc[1][c], 0, 0, 0);
                }
            }
        }
    }
    // mask from registers: same (row,col) elements this thread produced in stage 1
#pragma unroll
    for (int c = 0; c < 4; c++)
#pragma unroll
        for (int rt = 0; rt < 2; rt++)
#pragma unroll
            for (int r = 0; r < 4; r++) {
                float hv = h1f[rt][c][r];
                acc[rt][c][r] *= (1.f - hv * hv);
            }
    __syncthreads();
#pragma unroll
    for (int c = 0; c < 4; c++) {
        int col = w * 64 + c * 16 + lc;
#pragma unroll
        for (int rt = 0; rt < 2; rt++)
#pragma unroll
            for (int r = 0; r < 4; r++) {
                int row = rt * 16 + quad * 4 + r;
                sH1[row * STR + col] = f2bf(acc[rt][c][r]);
            }
    }
    __syncthreads();

    // ---- stage 7: g = dh1 @ W1^T (2 chunks of 8 frags) ----
    f32x4 acc7[2];
#pragma unroll
    for (int rt = 0; rt < 2; rt++) acc7[rt] = (f32x4)0.f;
    {
        const ushort_t* wbase = W1Tp + ((size_t)(e * 16) * 8 + w) * 512 + lane * 8;
#pragma unroll
        for (int ksc = 0; ksc < 2; ksc++) {
            BF8 bb[8];
#pragma unroll
            for (int kk = 0; kk < 8; kk++)
                bb[kk].f = *(const f32x4*)(wbase + (size_t)(ksc * 8 + kk) * 8 * 512);
#pragma unroll
            for (int kk = 0; kk < 8; kk++) {
                int ks = ksc * 8 + kk;
                bf16x8 a0 = *(const bf16x8*)((const char*)sH1 + lc * (STR * 2) + ks * 64 + quad * 16);
                bf16x8 a1 = *(const bf16x8*)((const char*)sH1 + (16 + lc) * (STR * 2) + ks * 64 + quad * 16);
                acc7[0] = __builtin_amdgcn_mfma_f32_16x16x32_bf16(a0, bb[kk].h, acc7[0], 0, 0, 0);
                acc7[1] = __builtin_amdgcn_mfma_f32_16x16x32_bf16(a1, bb[kk].h, acc7[1], 0, 0, 0);
            }
        }
    }
    {
        int col = w * 16 + lc;
#pragma unroll
        for (int rt = 0; rt < 2; rt++)
#pragma unroll
            for (int r = 0; r < 4; r++) {
                int row = rt * 16 + quad * 4 + r;
                if (col < FPD && row < nA)
                    g[(long long)sAtom[row] * FPD + col] = f2bf(acc7[rt][r]);
            }
    }
}

// scatter_lds for the fixed-capacity layout: bucket b occupies [b*BCAP, b*BCAP+cnt).
// Round-6 lesson: direct global atomicAdd into forces cost +54us (16-way
// cross-XCD same-address contention). Round-10 lesson: ticket-based fused
// reduction cost +105us (44-block serial reduce). forcesP slots + the broad
// reduce_forces pass is the measured optimum.
__global__ __launch_bounds__(256) void scatter_lds_cap(
    const u64_t* __restrict__ bpack, const int* __restrict__ bcnt,
    const ushort_t* __restrict__ g, float* __restrict__ forcesP) {
    __shared__ float facc[1 << CBITS];
    const int b = blockIdx.x >> 4;
    const int s = blockIdx.x & (NSLOT - 1);
    const int t = threadIdx.x;
    for (int i = t; i < (1 << CBITS); i += 256) facc[i] = 0.f;
    __syncthreads();
    const int base = b * BCAP;
    const int end = base + bcnt[b];
    for (int i = base + s * 256 + t; i < end; i += NSLOT * 256) {
        u64_t pk = bpack[i];
        int r = (int)(pk & 0x7FFFFFu);
        int cin = (int)((pk >> 23) & 0xFFFu);
        float v = bf2f((ushort_t)(pk >> 35));
        atomicAdd(&facc[cin], -v * bf2f(g[r]));
    }
    __syncthreads();
    const int colbase = b << CBITS;
    float* fp = forcesP + (size_t)s * NFORCE;
    for (int i = t; i < (1 << CBITS); i += 256) {
        int col = colbase + i;
        if (col < NFORCE) __builtin_nontemporal_store(facc[i], &fp[col]);
    }
}

// ---------------- fallback path kernels (round-0 exact) -----------------------
__global__ __launch_bounds__(256) void bucket_hist(const int* __restrict__ cols,
                                                   int* __restrict__ bcnt) {
    __shared__ int h[NBUCK];
    const int t = threadIdx.x;
    if (t < NBUCK) h[t] = 0;
    __syncthreads();
    const int nv = NNZ_C / 4;
    for (int vk = blockIdx.x * 256 + t; vk < nv; vk += gridDim.x * 256) {
        i32x4 c = __builtin_nontemporal_load((const i32x4*)cols + vk);
        atomicAdd(&h[c.x >> CBITS], 1);
        atomicAdd(&h[c.y >> CBITS], 1);
        atomicAdd(&h[c.z >> CBITS], 1);
        atomicAdd(&h[c.w >> CBITS], 1);
    }
    __syncthreads();
    if (t < NBUCK) atomicAdd(&bcnt[t], h[t]);
}

__global__ void bucket_scan(const int* __restrict__ bcnt, int* __restrict__ bbase,
                            int* __restrict__ bcur) {
    if (threadIdx.x == 0 && blockIdx.x == 0) {
        int s = 0;
        for (int i = 0; i < NBUCK; i++) { bbase[i] = s; bcur[i] = s; s += bcnt[i]; }
    }
}

__global__ __launch_bounds__(256) void bucket_scatter(
    const int* __restrict__ rows, const int* __restrict__ cols,
    const float* __restrict__ vals, int* __restrict__ bcur,
    u64_t* __restrict__ bpack) {
    __shared__ int lcnt[NBUCK];
    __shared__ int lcur[NBUCK];
    const int t = threadIdx.x;
    if (t < NBUCK) lcnt[t] = 0;
    __syncthreads();
    const int vk0 = blockIdx.x * 2048;
    i32x4 ccache[8];
    int nb[8][4];
#pragma unroll
    for (int i = 0; i < 8; i++) {
        int vk = vk0 + i * 256 + t;
        if (vk * 4 < NNZ_C) {
            i32x4 c = __builtin_nontemporal_load((const i32x4*)cols + vk);
            ccache[i] = c;
            nb[i][0] = c.x >> CBITS; nb[i][1] = c.y >> CBITS;
            nb[i][2] = c.z >> CBITS; nb[i][3] = c.w >> CBITS;
            atomicAdd(&lcnt[nb[i][0]], 1);
            atomicAdd(&lcnt[nb[i][1]], 1);
            atomicAdd(&lcnt[nb[i][2]], 1);
            atomicAdd(&lcnt[nb[i][3]], 1);
        } else {
            nb[i][0] = -1;
        }
    }
    __syncthreads();
    if (t < NBUCK) lcur[t] = atomicAdd(&bcur[t], lcnt[t]);
    __syncthreads();
#pragma unroll
    for (int i = 0; i < 8; i++) {
        int vk = vk0 + i * 256 + t;
        if (vk * 4 < NNZ_C) {
            i32x4 r = __builtin_nontemporal_load((const i32x4*)rows + vk);
            f32x4 v = __builtin_nontemporal_load((const f32x4*)vals + vk);
            int rr[4] = {r.x, r.y, r.z, r.w};
            int cc[4] = {ccache[i].x, ccache[i].y, ccache[i].z, ccache[i].w};
            float vv[4] = {v.x, v.y, v.z, v.w};
#pragma unroll
            for (int u = 0; u < 4; u++) {
                int pos = atomicAdd(&lcur[nb[i][u]], 1);
                u64_t pk = (u64_t)(uint_t)rr[u] |
                           ((u64_t)(uint_t)(cc[u] & ((1 << CBITS) - 1)) << 23) |
                           ((u64_t)f2bf(vv[u]) << 35);
                bpack[pos] = pk;
            }
        }
    }
}

__global__ __launch_bounds__(256) void scatter_lds(
    const u64_t* __restrict__ bpack, const int* __restrict__ bbase,
    const int* __restrict__ bcnt, const ushort_t* __restrict__ g,
    float* __restrict__ forcesP) {
    __shared__ float facc[1 << CBITS];
    const int b = blockIdx.x >> 4;
    const int s = blockIdx.x & (NSLOT - 1);
    const int t = threadIdx.x;
    for (int i = t; i < (1 << CBITS); i += 256) facc[i] = 0.f;
    __syncthreads();
    const int base = bbase[b];
    const int end = base + bcnt[b];
    for (int i = base + s * 256 + t; i < end; i += NSLOT * 256) {
        u64_t pk = bpack[i];
        int r = (int)(pk & 0x7FFFFFu);
        int cin = (int)((pk >> 23) & 0xFFFu);
        float v = bf2f((ushort_t)(pk >> 35));
        atomicAdd(&facc[cin], -v * bf2f(g[r]));
    }
    __syncthreads();
    const int colbase = b << CBITS;
    float* fp = forcesP + (size_t)s * NFORCE;
    for (int i = t; i < (1 << CBITS); i += 256) {
        int col = colbase + i;
        if (col < NFORCE) __builtin_nontemporal_store(facc[i], &fp[col]);
    }
}

__global__ void reduce_forces(const float* __restrict__ forcesP, float* __restrict__ forces) {
    int i = blockIdx.x * blockDim.x + threadIdx.x;
    if (i >= NFORCE) return;
    float s = 0.f;
#pragma unroll
    for (int x = 0; x < NSLOT; x++) s += forcesP[(size_t)x * NFORCE + i];
    forces[i] = s;
}

__global__ __launch_bounds__(256) void scatter_forces(
    const int* __restrict__ rows, const int* __restrict__ cols,
    const float* __restrict__ vals, const ushort_t* __restrict__ g,
    float* __restrict__ forcesP) {
    int k = blockIdx.x * 256 + threadIdx.x;
    if (k >= NNZ_C / 4) return;
    int slot = blockIdx.x & (NSLOT - 1);
    i32x4 r = __builtin_nontemporal_load((const i32x4*)rows + k);
    i32x4 c = __builtin_nontemporal_load((const i32x4*)cols + k);
    f32x4 v = __builtin_nontemporal_load((const f32x4*)vals + k);
    float* fp = forcesP + (size_t)slot * NFORCE;
    atomicAdd(&fp[c.x], -v.x * bf2f(g[r.x]));
    atomicAdd(&fp[c.y], -v.y * bf2f(g[r.y]));
    atomicAdd(&fp[c.z], -v.z * bf2f(g[r.z]));
    atomicAdd(&fp[c.w], -v.w * bf2f(g[r.w]));
}

extern "C" void kernel_launch(void* const* d_in, const int* in_sizes, int n_in,
                              void* d_out, int out_size, void* d_ws, size_t ws_size,
                              hipStream_t stream) {
    const float* fps = (const float*)d_in[0];
    const int* z = (const int*)d_in[1];
    const int* img = (const int*)d_in[2];
    const float* W1 = (const float*)d_in[3];
    const float* b1 = (const float*)d_in[4];
    const float* W2 = (const float*)d_in[5];
    const float* b2 = (const float*)d_in[6];
    const float* W3 = (const float*)d_in[7];
    const float* b3 = (const float*)d_in[8];
    const int* rows = (const int*)d_in[9];
    const int* cols = (const int*)d_in[10];
    const float* vals = (const float*)d_in[11];

    float* out = (float*)d_out;
    float* energy = out;
    float* forces = out + BB;

    char* ws = (char*)d_ws;
    int* counts = (int*)ws;                           // 256 B
    int* lists = (int*)(ws + 256);                    // 720000 B
    ushort_t* W1p = (ushort_t*)(ws + 720384);         // 393216 B
    ushort_t* W2p = (ushort_t*)(ws + 1113600);        // 1572864 B
    ushort_t* W2Tp = (ushort_t*)(ws + 2686464);       // 1572864 B
    ushort_t* W1Tp = (ushort_t*)(ws + 4259328);       // 393216 B
    ushort_t* g = (ushort_t*)(ws + 4652544);          // 14400000 B
    float* forcesP = (float*)(ws + 19052544);         // 16*720000 = 11520000 B
    int* bmeta = (int*)(ws + 30572544);               // bcnt[64],bbase[64],bcur[64]
    int* bcnt = bmeta, *bbase = bmeta + 64, *bcur = bmeta + 128;
    u64_t* bpack = (u64_t*)(ws + 30573568);
    const size_t WS_FAST = 30573568ull + (size_t)NBUCK * BCAP * 8;  // 72,109,568
    const size_t WS_NEED = 70573568;                                // packed layout
    (void)in_sizes; (void)n_in; (void)out_size;

    (void)hipMemsetAsync(energy, 0, BB * sizeof(float), stream);
    (void)hipMemsetAsync(counts, 0, 256, stream);

    build_lists<<<(N_ATOMS + 255) / 256, 256, 0, stream>>>(z, counts, lists);
    pack_all<<<(R_W2 + R_W1 + R_W1T + 255) / 256, 256, 0, stream>>>(
        W1, W2, W1p, W2p, W2Tp, W1Tp);

    int tiles = (N_ATOMS + TB - 1) / TB;

    if (ws_size >= WS_FAST) {
        // fast path: fused scatter+MLP (e-major); forcesP slots + reduce
        (void)hipMemsetAsync(bmeta, 0, 768, stream);
        mlp_mfma<<<SCAT_BLOCKS + EE * TPE, 512, 0, stream>>>(
            fps, img, b1, b2, W3, b3, W1p, W2p, W2Tp, W1Tp,
            counts, lists, energy, g,
            rows, cols, vals, bcnt, bpack, SCAT_BLOCKS);
        scatter_lds_cap<<<NBUCK * NSLOT, 256, 0, stream>>>(bpack, bcnt, g, forcesP);
        reduce_forces<<<(NFORCE + 255) / 256, 256, 0, stream>>>(forcesP, forces);
    } else if (ws_size >= WS_NEED) {
        // round-0 path: serial hist/scan/scatter with packed buckets
        (void)hipMemsetAsync(bmeta, 0, 768, stream);
        mlp_mfma<<<EE * tiles, 512, 0, stream>>>(
            fps, img, b1, b2, W3, b3, W1p, W2p, W2Tp, W1Tp,
            counts, lists, energy, g,
            rows, cols, vals, bcnt, bpack, 0);
        bucket_hist<<<256, 256, 0, stream>>>(cols, bcnt);
        bucket_scan<<<1, 64, 0, stream>>>(bcnt, bbase, bcur);
        bucket_scatter<<<(NNZ_C + 8191) / 8192, 256, 0, stream>>>(
            rows, cols, vals, bcur, bpack);
        scatter_lds<<<NBUCK * NSLOT, 256, 0, stream>>>(bpack, bbase, bcnt, g, forcesP);
        reduce_forces<<<(NFORCE + 255) / 256, 256, 0, stream>>>(forcesP, forces);
    } else {
        (void)hipMemsetAsync(forcesP, 0, (size_t)NSLOT * NFORCE * sizeof(float), stream);
        mlp_mfma<<<EE * tiles, 512, 0, stream>>>(
            fps, img, b1, b2, W3, b3, W1p, W2p, W2Tp, W1Tp,
            counts, lists, energy, g,
            rows, cols, vals, bcnt, (u64_t*)forcesP /*unused*/, 0);
        scatter_forces<<<(NNZ_C / 4 + 255) / 256, 256, 0, stream>>>(rows, cols, vals, g, forcesP);
        reduce_forces<<<(NFORCE + 255) / 256, 256, 0, stream>>>(forcesP, forces);
    }
}